// Round 6
// baseline (240.113 us; speedup 1.0000x reference)
//
#include <hip/hip_runtime.h>
#include <cmath>

#define N_NODES 50000
#define N_EDGES 800000
#define D 64
#define N_REL 8

#define NODES_PER_BLK 32
#define CSTRIDE 132                 // 128 + 4 pad; float4 rows stay 16B-aligned
#define NB_SCAN 196                 // ceil(50000/256)
#define TN 16                       // nodes per block in tables_kernel

// ---------------------------------------------------------------------------
// K0: w[r*128 + j] = sum_k W_r[r][j][k]
// ---------------------------------------------------------------------------
__global__ void wprep_kernel(const float* __restrict__ W_r, float* __restrict__ w) {
    int t = blockIdx.x * blockDim.x + threadIdx.x;
    if (t >= N_REL * 2 * D) return;
    const float* p = W_r + (size_t)t * D;
    float s = 0.0f;
#pragma unroll
    for (int k = 0; k < D; ++k) s += p[k];
    w[t] = s;
}

// ---------------------------------------------------------------------------
// K1: logit tables as a tall-skinny GEMM: T[n][q] = <x[n], w_row_q>.
// ---------------------------------------------------------------------------
__global__ __launch_bounds__(256) void tables_kernel(
    const float* __restrict__ x, const float* __restrict__ w,
    float* __restrict__ Dn, float* __restrict__ Sr)
{
    __shared__ float xs[TN][68];
    __shared__ float ws[16][68];

    int tid = threadIdx.x;
    int n0  = blockIdx.x * TN;

    for (int i = tid; i < 16 * 64; i += 256)
        ws[i >> 6][i & 63] = w[i];
    for (int i = tid; i < TN * 64; i += 256) {
        int n = n0 + (i >> 6);
        xs[i >> 6][i & 63] = (n < N_NODES) ? x[(size_t)n * D + (i & 63)] : 0.f;
    }
    __syncthreads();

    int q = tid & 15, nl = tid >> 4;
    float acc = 0.f;
#pragma unroll
    for (int k = 0; k < 64; k += 4) {
        float4 a = *(const float4*)&xs[nl][k];
        float4 b = *(const float4*)&ws[q][k];
        acc += a.x * b.x + a.y * b.y + a.z * b.z + a.w * b.w;
    }
    int n = n0 + nl;
    if (n < N_NODES) {
        int r = q >> 1;
        if ((q & 1) == 0) Dn[n * 8 + r] = acc;
        else              Sr[n * 8 + r] = acc;
    }
}

// ---------------------------------------------------------------------------
// K2: degree histogram
// ---------------------------------------------------------------------------
__global__ void hist_kernel(const int* __restrict__ dst, int* __restrict__ cnt) {
    int e = blockIdx.x * blockDim.x + threadIdx.x;
    if (e < N_EDGES) atomicAdd(&cnt[dst[e]], 1);
}

// ---------------------------------------------------------------------------
// K3a/b/c: exclusive scan of cnt -> row_ptr (and woff working copy)
// ---------------------------------------------------------------------------
__global__ __launch_bounds__(256) void scanA(const int* __restrict__ cnt,
                                             int* __restrict__ excl,
                                             int* __restrict__ partial) {
    __shared__ int s[256];
    int t = threadIdx.x;
    int i = blockIdx.x * 256 + t;
    int v = (i < N_NODES) ? cnt[i] : 0;
    s[t] = v;
    __syncthreads();
    for (int off = 1; off < 256; off <<= 1) {
        int add = (t >= off) ? s[t - off] : 0;
        __syncthreads();
        s[t] += add;
        __syncthreads();
    }
    if (i < N_NODES) excl[i] = s[t] - v;
    if (t == 255) partial[blockIdx.x] = s[255];
}

__global__ __launch_bounds__(256) void scanB(int* __restrict__ partial) {
    __shared__ int s[256];
    int t = threadIdx.x;
    int v = (t < NB_SCAN) ? partial[t] : 0;
    s[t] = v;
    __syncthreads();
    for (int off = 1; off < 256; off <<= 1) {
        int add = (t >= off) ? s[t - off] : 0;
        __syncthreads();
        s[t] += add;
        __syncthreads();
    }
    if (t < NB_SCAN) partial[t] = s[t] - v;
}

__global__ __launch_bounds__(256) void scanC(const int* __restrict__ excl,
                                             const int* __restrict__ partial,
                                             int* __restrict__ row_ptr,
                                             int* __restrict__ woff) {
    int i = blockIdx.x * 256 + threadIdx.x;
    if (i < N_NODES) {
        int rp = excl[i] + partial[i >> 8];
        row_ptr[i] = rp;
        woff[i] = rp;
    }
    if (i == N_NODES) row_ptr[N_NODES] = N_EDGES;
}

// ---------------------------------------------------------------------------
// K4: scatter edges into CSR order, packed 4B: src | (rel<<20).
// R5's 8B (gate,src) scatter moved 92MB HBM (write-allocate on random 8B
// stores + 1.6M Dn/Sr gathers). 4B payload into a 3.2MB region stays
// L2-resident; gate computation moved to agg where Dn is wave-local.
// ---------------------------------------------------------------------------
__global__ void scatter_kernel(const int* __restrict__ src, const int* __restrict__ dst,
                               const int* __restrict__ rel,
                               int* __restrict__ woff, int* __restrict__ epack) {
    int e = blockIdx.x * blockDim.x + threadIdx.x;
    if (e >= N_EDGES) return;
    int d = dst[e];
    int pos = atomicAdd(&woff[d], 1);
    epack[pos] = src[e] | (rel[e] << 20);
}

// ---------------------------------------------------------------------------
// K5: aggregation + gate. One wave per node, lane = dim.
// Gate: Dn[n*8+r] is wave-local (32B), Sr[s*8+r] is an L2-resident gather.
// ---------------------------------------------------------------------------
__global__ __launch_bounds__(256) void agg_kernel(
    const float* __restrict__ x,
    const int*   __restrict__ row_ptr,
    const int*   __restrict__ epack,
    const float* __restrict__ Dn,
    const float* __restrict__ Sr,
    float* __restrict__ agg)           // (N_NODES, 64) normalized
{
    int n    = (blockIdx.x * blockDim.x + threadIdx.x) >> 6;
    int lane = threadIdx.x & 63;
    if (n >= N_NODES) return;

    int beg = row_ptr[n], end = row_ptr[n + 1];
    const float* DnN = Dn + n * 8;
    float acc = 0.f;

    for (int base = beg; base < end; base += 64) {
        int m = end - base; if (m > 64) m = 64;
        float g = 0.f; int s = 0;
        if (lane < m) {
            int pk = epack[base + lane];
            s = pk & 0xFFFFF;
            int r = pk >> 20;
            float logit = DnN[r] + Sr[s * 8 + r];
            g = 1.0f / (1.0f + __expf(-logit));
        }
        int mm = (m + 7) & ~7;   // inactive slots have g=0,s=0 -> harmless
        for (int j = 0; j < mm; j += 8) {
            float gg[8]; int ss[8];
#pragma unroll
            for (int u = 0; u < 8; ++u) {
                gg[u] = __shfl(g, j + u, 64);
                ss[u] = __shfl(s, j + u, 64);
            }
            float vv[8];
#pragma unroll
            for (int u = 0; u < 8; ++u) vv[u] = x[(size_t)ss[u] * D + lane];
#pragma unroll
            for (int u = 0; u < 8; ++u) acc += gg[u] * vv[u];
        }
    }
    float inv = 1.0f / fmaxf((float)(end - beg), 1.0f);
    agg[(size_t)n * D + lane] = acc * inv;
}

// ---------------------------------------------------------------------------
// K6: out = leaky_relu([x, agg] @ W_lin^T + b). Block = 256 thr, 32 nodes.
// __launch_bounds__(256,4) caps VGPR at 128; #pragma unroll 2 keeps the
// ds_read live-set small (full unroll spilled: VGPR=256, 437MB scratch).
// ---------------------------------------------------------------------------
__global__ __launch_bounds__(256, 4) void lin_kernel(
    const float* __restrict__ x,
    const float* __restrict__ agg,
    const float* __restrict__ W_lin,
    const float* __restrict__ b_lin,
    float* __restrict__ out)
{
    __shared__ float c_lds[NODES_PER_BLK][CSTRIDE];
    __shared__ float W_lds[64][CSTRIDE];
    __shared__ float b_lds[64];

    int tid  = threadIdx.x;
    int wid  = tid >> 6;
    int lane = tid & 63;
    int n0   = blockIdx.x * NODES_PER_BLK;

    for (int i = tid; i < 64 * 128; i += 256)
        W_lds[i >> 7][i & 127] = W_lin[i];
    if (tid < 64) b_lds[tid] = b_lin[tid];

#pragma unroll
    for (int it = 0; it < NODES_PER_BLK / 4; ++it) {
        int nl = wid * (NODES_PER_BLK / 4) + it;
        int n  = n0 + nl;
        if (n < N_NODES) {
            c_lds[nl][lane]      = x[(size_t)n * D + lane];
            c_lds[nl][64 + lane] = agg[(size_t)n * D + lane];
        } else {
            c_lds[nl][lane] = 0.f;
            c_lds[nl][64 + lane] = 0.f;
        }
    }
    __syncthreads();

    int tx = tid & 15, ty = tid >> 4;
    float acc[2][4];
#pragma unroll
    for (int i = 0; i < 2; ++i)
#pragma unroll
        for (int jj = 0; jj < 4; ++jj) acc[i][jj] = b_lds[tx + 16 * jj];

#pragma unroll 2
    for (int k = 0; k < 128; k += 4) {
        float4 cv[2], wv[4];
        cv[0] = *(const float4*)&c_lds[ty][k];
        cv[1] = *(const float4*)&c_lds[ty + 16][k];
#pragma unroll
        for (int jj = 0; jj < 4; ++jj)
            wv[jj] = *(const float4*)&W_lds[tx + 16 * jj][k];
#pragma unroll
        for (int i = 0; i < 2; ++i)
#pragma unroll
            for (int jj = 0; jj < 4; ++jj)
                acc[i][jj] += cv[i].x * wv[jj].x + cv[i].y * wv[jj].y
                            + cv[i].z * wv[jj].z + cv[i].w * wv[jj].w;
    }

#pragma unroll
    for (int i = 0; i < 2; ++i) {
        int n = n0 + ty + 16 * i;
        if (n < N_NODES) {
#pragma unroll
            for (int jj = 0; jj < 4; ++jj) {
                float v = acc[i][jj];
                out[(size_t)n * D + tx + 16 * jj] = (v > 0.f) ? v : 0.01f * v;
            }
        }
    }
}

// ---------------------------------------------------------------------------
extern "C" void kernel_launch(void* const* d_in, const int* in_sizes, int n_in,
                              void* d_out, int out_size, void* d_ws, size_t ws_size,
                              hipStream_t stream) {
    const float* x     = (const float*)d_in[0];
    const int*   src   = (const int*)  d_in[1];
    const int*   dst   = (const int*)  d_in[2];
    const int*   rel   = (const int*)  d_in[3];
    const float* W_r   = (const float*)d_in[4];
    const float* W_lin = (const float*)d_in[5];
    const float* b_lin = (const float*)d_in[6];
    float* out = (float*)d_out;

    char* p = (char*)d_ws;
    float*  w       = (float*)p;                p += 4096;
    float*  Dn      = (float*)p;                p += (size_t)N_NODES * 8 * 4;
    float*  Sr      = (float*)p;                p += (size_t)N_NODES * 8 * 4;
    int*    cnt     = (int*)p;                  p += (size_t)N_NODES * 4;
    int*    excl    = (int*)p;                  p += (size_t)N_NODES * 4;
    int*    row_ptr = (int*)p;                  p += (size_t)(N_NODES + 64) * 4;
    int*    woff    = (int*)p;                  p += (size_t)N_NODES * 4;
    int*    partial = (int*)p;                  p += 1024;
    float*  agg     = (float*)p;                p += (size_t)N_NODES * D * 4;   // 12.8 MB
    int*    epack   = (int*)p;                  p += (size_t)N_EDGES * 4;       // 3.2 MB

    hipMemsetAsync(cnt, 0, (size_t)N_NODES * sizeof(int), stream);

    wprep_kernel<<<4, 256, 0, stream>>>(W_r, w);
    tables_kernel<<<(N_NODES + TN - 1) / TN, 256, 0, stream>>>(x, w, Dn, Sr);
    hist_kernel<<<(N_EDGES + 255) / 256, 256, 0, stream>>>(dst, cnt);
    scanA<<<NB_SCAN, 256, 0, stream>>>(cnt, excl, partial);
    scanB<<<1, 256, 0, stream>>>(partial);
    scanC<<<NB_SCAN, 256, 0, stream>>>(excl, partial, row_ptr, woff);
    scatter_kernel<<<(N_EDGES + 255) / 256, 256, 0, stream>>>(src, dst, rel, woff, epack);
    agg_kernel<<<(N_NODES * 64 + 255) / 256, 256, 0, stream>>>(x, row_ptr, epack, Dn, Sr, agg);
    lin_kernel<<<(N_NODES + NODES_PER_BLK - 1) / NODES_PER_BLK, 256, 0, stream>>>(
        x, agg, W_lin, b_lin, out);
}

// Round 7
// 211.656 us; speedup vs baseline: 1.1344x; 1.1344x over previous
//
#include <hip/hip_runtime.h>
#include <cmath>

#define N_NODES 50000
#define N_EDGES 800000
#define D 64
#define N_REL 8

#define NODES_PER_BLK 32
#define CSTRIDE 132                 // 128 + 4 pad; float4 rows stay 16B-aligned
#define NB_SCAN 196                 // ceil(50000/256)
#define TN 16                       // nodes per block in tables_kernel

// ---------------------------------------------------------------------------
// K0: w[r*128 + j] = sum_k W_r[r][j][k]
// ---------------------------------------------------------------------------
__global__ void wprep_kernel(const float* __restrict__ W_r, float* __restrict__ w) {
    int t = blockIdx.x * blockDim.x + threadIdx.x;
    if (t >= N_REL * 2 * D) return;
    const float* p = W_r + (size_t)t * D;
    float s = 0.0f;
#pragma unroll
    for (int k = 0; k < D; ++k) s += p[k];
    w[t] = s;
}

// ---------------------------------------------------------------------------
// K1: logit tables as a tall-skinny GEMM: T[n][q] = <x[n], w_row_q>.
// ---------------------------------------------------------------------------
__global__ __launch_bounds__(256) void tables_kernel(
    const float* __restrict__ x, const float* __restrict__ w,
    float* __restrict__ Dn, float* __restrict__ Sr)
{
    __shared__ float xs[TN][68];
    __shared__ float ws[16][68];

    int tid = threadIdx.x;
    int n0  = blockIdx.x * TN;

    for (int i = tid; i < 16 * 64; i += 256)
        ws[i >> 6][i & 63] = w[i];
    for (int i = tid; i < TN * 64; i += 256) {
        int n = n0 + (i >> 6);
        xs[i >> 6][i & 63] = (n < N_NODES) ? x[(size_t)n * D + (i & 63)] : 0.f;
    }
    __syncthreads();

    int q = tid & 15, nl = tid >> 4;
    float acc = 0.f;
#pragma unroll
    for (int k = 0; k < 64; k += 4) {
        float4 a = *(const float4*)&xs[nl][k];
        float4 b = *(const float4*)&ws[q][k];
        acc += a.x * b.x + a.y * b.y + a.z * b.z + a.w * b.w;
    }
    int n = n0 + nl;
    if (n < N_NODES) {
        int r = q >> 1;
        if ((q & 1) == 0) Dn[n * 8 + r] = acc;
        else              Sr[n * 8 + r] = acc;
    }
}

// ---------------------------------------------------------------------------
// K2: degree histogram THAT KEEPS THE RANK. rank[e] = my index within dst row.
// This is the only device-atomic pass; scatter reuses rank instead of
// doing a second 800K-atomic pass.
// ---------------------------------------------------------------------------
__global__ void rank_kernel(const int* __restrict__ dst,
                            int* __restrict__ cnt, int* __restrict__ rank) {
    int e = blockIdx.x * blockDim.x + threadIdx.x;
    if (e < N_EDGES) rank[e] = atomicAdd(&cnt[dst[e]], 1);
}

// ---------------------------------------------------------------------------
// K3a/b/c: exclusive scan of cnt -> row_ptr
// ---------------------------------------------------------------------------
__global__ __launch_bounds__(256) void scanA(const int* __restrict__ cnt,
                                             int* __restrict__ excl,
                                             int* __restrict__ partial) {
    __shared__ int s[256];
    int t = threadIdx.x;
    int i = blockIdx.x * 256 + t;
    int v = (i < N_NODES) ? cnt[i] : 0;
    s[t] = v;
    __syncthreads();
    for (int off = 1; off < 256; off <<= 1) {
        int add = (t >= off) ? s[t - off] : 0;
        __syncthreads();
        s[t] += add;
        __syncthreads();
    }
    if (i < N_NODES) excl[i] = s[t] - v;
    if (t == 255) partial[blockIdx.x] = s[255];
}

__global__ __launch_bounds__(256) void scanB(int* __restrict__ partial) {
    __shared__ int s[256];
    int t = threadIdx.x;
    int v = (t < NB_SCAN) ? partial[t] : 0;
    s[t] = v;
    __syncthreads();
    for (int off = 1; off < 256; off <<= 1) {
        int add = (t >= off) ? s[t - off] : 0;
        __syncthreads();
        s[t] += add;
        __syncthreads();
    }
    if (t < NB_SCAN) partial[t] = s[t] - v;
}

__global__ __launch_bounds__(256) void scanC(const int* __restrict__ excl,
                                             const int* __restrict__ partial,
                                             int* __restrict__ row_ptr) {
    int i = blockIdx.x * 256 + threadIdx.x;
    if (i < N_NODES) row_ptr[i] = excl[i] + partial[i >> 8];
    if (i == N_NODES) row_ptr[N_NODES] = N_EDGES;
}

// ---------------------------------------------------------------------------
// K4: scatter edges into CSR order with gate precomputed. NO ATOMICS:
// pos = row_ptr[dst] + rank[e]. epack[pos] = (gate, src-bits).
// Duration of this kernel now = pure gather + random-store cost.
// ---------------------------------------------------------------------------
__global__ void scatter_kernel(const int* __restrict__ src, const int* __restrict__ dst,
                               const int* __restrict__ rel, const int* __restrict__ rank,
                               const int* __restrict__ row_ptr,
                               const float* __restrict__ Dn, const float* __restrict__ Sr,
                               float2* __restrict__ epack) {
    int e = blockIdx.x * blockDim.x + threadIdx.x;
    if (e >= N_EDGES) return;
    int s = src[e], d = dst[e], r = rel[e];
    float logit = Dn[d * 8 + r] + Sr[s * 8 + r];
    float gate = 1.0f / (1.0f + __expf(-logit));
    int pos = row_ptr[d] + rank[e];
    float2 v; v.x = gate; v.y = __int_as_float(s);
    epack[pos] = v;
}

// ---------------------------------------------------------------------------
// K5: aggregation. One wave per node, lane = dim. (R5 form: gate preloaded.)
// ---------------------------------------------------------------------------
__global__ __launch_bounds__(256) void agg_kernel(
    const float* __restrict__ x,
    const int*   __restrict__ row_ptr,
    const float2* __restrict__ epack,
    float* __restrict__ agg)           // (N_NODES, 64) normalized
{
    int n    = (blockIdx.x * blockDim.x + threadIdx.x) >> 6;
    int lane = threadIdx.x & 63;
    if (n >= N_NODES) return;

    int beg = row_ptr[n], end = row_ptr[n + 1];
    float acc = 0.f;

    for (int base = beg; base < end; base += 64) {
        int m = end - base; if (m > 64) m = 64;
        float g = 0.f; int s = 0;
        if (lane < m) {
            float2 v = epack[base + lane];
            g = v.x; s = __float_as_int(v.y);
        }
        int mm = (m + 7) & ~7;   // inactive slots have g=0,s=0 -> harmless
        for (int j = 0; j < mm; j += 8) {
            float gg[8]; int ss[8];
#pragma unroll
            for (int u = 0; u < 8; ++u) {
                gg[u] = __shfl(g, j + u, 64);
                ss[u] = __shfl(s, j + u, 64);
            }
            float vv[8];
#pragma unroll
            for (int u = 0; u < 8; ++u) vv[u] = x[(size_t)ss[u] * D + lane];
#pragma unroll
            for (int u = 0; u < 8; ++u) acc += gg[u] * vv[u];
        }
    }
    float inv = 1.0f / fmaxf((float)(end - beg), 1.0f);
    agg[(size_t)n * D + lane] = acc * inv;
}

// ---------------------------------------------------------------------------
// K6: out = leaky_relu([x, agg] @ W_lin^T + b). Block = 256 thr, 32 nodes.
// ---------------------------------------------------------------------------
__global__ __launch_bounds__(256, 4) void lin_kernel(
    const float* __restrict__ x,
    const float* __restrict__ agg,
    const float* __restrict__ W_lin,
    const float* __restrict__ b_lin,
    float* __restrict__ out)
{
    __shared__ float c_lds[NODES_PER_BLK][CSTRIDE];
    __shared__ float W_lds[64][CSTRIDE];
    __shared__ float b_lds[64];

    int tid  = threadIdx.x;
    int wid  = tid >> 6;
    int lane = tid & 63;
    int n0   = blockIdx.x * NODES_PER_BLK;

    for (int i = tid; i < 64 * 128; i += 256)
        W_lds[i >> 7][i & 127] = W_lin[i];
    if (tid < 64) b_lds[tid] = b_lin[tid];

#pragma unroll
    for (int it = 0; it < NODES_PER_BLK / 4; ++it) {
        int nl = wid * (NODES_PER_BLK / 4) + it;
        int n  = n0 + nl;
        if (n < N_NODES) {
            c_lds[nl][lane]      = x[(size_t)n * D + lane];
            c_lds[nl][64 + lane] = agg[(size_t)n * D + lane];
        } else {
            c_lds[nl][lane] = 0.f;
            c_lds[nl][64 + lane] = 0.f;
        }
    }
    __syncthreads();

    int tx = tid & 15, ty = tid >> 4;
    float acc[2][4];
#pragma unroll
    for (int i = 0; i < 2; ++i)
#pragma unroll
        for (int jj = 0; jj < 4; ++jj) acc[i][jj] = b_lds[tx + 16 * jj];

#pragma unroll 2
    for (int k = 0; k < 128; k += 4) {
        float4 cv[2], wv[4];
        cv[0] = *(const float4*)&c_lds[ty][k];
        cv[1] = *(const float4*)&c_lds[ty + 16][k];
#pragma unroll
        for (int jj = 0; jj < 4; ++jj)
            wv[jj] = *(const float4*)&W_lds[tx + 16 * jj][k];
#pragma unroll
        for (int i = 0; i < 2; ++i)
#pragma unroll
            for (int jj = 0; jj < 4; ++jj)
                acc[i][jj] += cv[i].x * wv[jj].x + cv[i].y * wv[jj].y
                            + cv[i].z * wv[jj].z + cv[i].w * wv[jj].w;
    }

#pragma unroll
    for (int i = 0; i < 2; ++i) {
        int n = n0 + ty + 16 * i;
        if (n < N_NODES) {
#pragma unroll
            for (int jj = 0; jj < 4; ++jj) {
                float v = acc[i][jj];
                out[(size_t)n * D + tx + 16 * jj] = (v > 0.f) ? v : 0.01f * v;
            }
        }
    }
}

// ---------------------------------------------------------------------------
extern "C" void kernel_launch(void* const* d_in, const int* in_sizes, int n_in,
                              void* d_out, int out_size, void* d_ws, size_t ws_size,
                              hipStream_t stream) {
    const float* x     = (const float*)d_in[0];
    const int*   src   = (const int*)  d_in[1];
    const int*   dst   = (const int*)  d_in[2];
    const int*   rel   = (const int*)  d_in[3];
    const float* W_r   = (const float*)d_in[4];
    const float* W_lin = (const float*)d_in[5];
    const float* b_lin = (const float*)d_in[6];
    float* out = (float*)d_out;

    char* p = (char*)d_ws;
    float*  w       = (float*)p;                p += 4096;
    float*  Dn      = (float*)p;                p += (size_t)N_NODES * 8 * 4;   // 1.6 MB
    float*  Sr      = (float*)p;                p += (size_t)N_NODES * 8 * 4;   // 1.6 MB
    int*    cnt     = (int*)p;                  p += (size_t)N_NODES * 4;
    int*    excl    = (int*)p;                  p += (size_t)N_NODES * 4;
    int*    row_ptr = (int*)p;                  p += (size_t)(N_NODES + 64) * 4;
    int*    partial = (int*)p;                  p += 1024;
    int*    rank    = (int*)p;                  p += (size_t)N_EDGES * 4;       // 3.2 MB
    float*  agg     = (float*)p;                p += (size_t)N_NODES * D * 4;   // 12.8 MB
    float2* epack   = (float2*)p;               p += (size_t)N_EDGES * 8;       // 6.4 MB

    hipMemsetAsync(cnt, 0, (size_t)N_NODES * sizeof(int), stream);

    wprep_kernel<<<4, 256, 0, stream>>>(W_r, w);
    tables_kernel<<<(N_NODES + TN - 1) / TN, 256, 0, stream>>>(x, w, Dn, Sr);
    rank_kernel<<<(N_EDGES + 255) / 256, 256, 0, stream>>>(dst, cnt, rank);
    scanA<<<NB_SCAN, 256, 0, stream>>>(cnt, excl, partial);
    scanB<<<1, 256, 0, stream>>>(partial);
    scanC<<<NB_SCAN, 256, 0, stream>>>(excl, partial, row_ptr);
    scatter_kernel<<<(N_EDGES + 255) / 256, 256, 0, stream>>>(src, dst, rel, rank, row_ptr,
                                                              Dn, Sr, epack);
    agg_kernel<<<(N_NODES * 64 + 255) / 256, 256, 0, stream>>>(x, row_ptr, epack, agg);
    lin_kernel<<<(N_NODES + NODES_PER_BLK - 1) / NODES_PER_BLK, 256, 0, stream>>>(
        x, agg, W_lin, b_lin, out);
}